// Round 8
// baseline (5360.851 us; speedup 1.0000x reference)
//
#include <hip/hip_runtime.h>

// ---------------------------------------------------------------------------
// Fake-quant self-attention, B=8 S=1024 D=1024, bit=8 — BITWISE f32 numpy
// replication.
//
// Evidence: R2==R5 (1.513672e-2) and R6==R7 (1.867676e-2) bit-identical
// across wildly different matmul precisions; f64-exact logits (R7) did NOT
// fix it, and more-exact epilogues made it WORSE. => The np reference is
// FLOAT32 end-to-end and contains its own rounding-noise fq flips; an exact
// implementation deterministically misses them.  Fix: replicate numpy's f32
// arithmetic bit-for-bit:
//  * einsum contractions (Q,K,V,QK^T): numpy einsum_sumprod contig_two at
//    x86 BASELINE SIMD (SSE3): 4 strided accumulators (k mod 4), UNFUSED
//    mul+add, combine (a0+a1)+(a2+a3).  __fmul_rn/__fadd_rn block fp-contract.
//  * PV einsum (V operand non-contig): generic loop = strictly sequential-j
//    unfused mul+add per output element.
//  * softmax: m = exact row max; e = f32(exp_f64(l-m)) (≈correctly-rounded
//    f32 exp); S = numpy pairwise_sum (128-blocks, 8 accums, exact tree);
//    p = e/S (IEEE f32 div); pmax = max(1.0f/S).
//  * every fake_quant: f32 mul, rintf (RNE = np.round), clip, IEEE f32 div.
// Residual vs ref: numpy's SIMD exp differs ~1-2 ulp -> few hundred 1-step
// p-quant flips, each <= step_p*|V| ~ 4.7e-3 < threshold 9.49e-3.
// ---------------------------------------------------------------------------

typedef unsigned u32;
#define DEV __device__ __forceinline__

DEV float fmul(float a, float b) { return __fmul_rn(a, b); }   // no contract
DEV float fadd(float a, float b) { return __fadd_rn(a, b); }   // no contract
DEV float clip8f(float v) { return fminf(fmaxf(v, -128.f), 127.f); }
DEV float ldb(const u32* p, int i) { return __builtin_bit_cast(float, p[i]); }
DEV float wmaxf(float m) {
    #pragma unroll
    for (int off = 32; off; off >>= 1) m = fmaxf(m, __shfl_xor(m, off));
    return m;
}
DEV float expf_np(float x) { return (float)exp((double)x); }   // ~CR f32 exp

// numpy pairwise_sum 128-block: 8 accumulators, exact combine tree
DEV float np_block128(const float* a) {
    float r0=a[0],r1=a[1],r2=a[2],r3=a[3],r4=a[4],r5=a[5],r6=a[6],r7=a[7];
    for (int i = 8; i < 128; i += 8) {
        r0 = fadd(r0, a[i+0]); r1 = fadd(r1, a[i+1]);
        r2 = fadd(r2, a[i+2]); r3 = fadd(r3, a[i+3]);
        r4 = fadd(r4, a[i+4]); r5 = fadd(r5, a[i+5]);
        r6 = fadd(r6, a[i+6]); r7 = fadd(r7, a[i+7]);
    }
    return fadd(fadd(fadd(r0,r1), fadd(r2,r3)), fadd(fadd(r4,r5), fadd(r6,r7)));
}
// pairwise for n=1024: ((B0+B1)+(B2+B3)) + ((B4+B5)+(B6+B7))
DEV float np_pair1024(const float* a) {
    float b0 = np_block128(a +   0), b1 = np_block128(a + 128);
    float b2 = np_block128(a + 256), b3 = np_block128(a + 384);
    float b4 = np_block128(a + 512), b5 = np_block128(a + 640);
    float b6 = np_block128(a + 768), b7 = np_block128(a + 896);
    return fadd(fadd(fadd(b0,b1), fadd(b2,b3)), fadd(fadd(b4,b5), fadd(b6,b7)));
}

// scal: 0=amax_wq 1=amax_wk 2=amax_wv 3=amax_atten 4=pmax 5=amax_out (f32 bits)
__global__ void init_kernel(u32* scal) {
    if (threadIdx.x < 8) scal[threadIdx.x] = 0u;
}

__global__ void amax_w_kernel(const float* __restrict__ wq, const float* __restrict__ wk,
                              const float* __restrict__ wv, u32* __restrict__ scal) {
    const int z = blockIdx.z;
    const float* w = z == 0 ? wq : z == 1 ? wk : wv;
    int idx = blockIdx.x * 256 + threadIdx.x;
    float m = 0.f;
    for (int i = idx; i < 262144; i += 32768) {
        float4 v = ((const float4*)w)[i];
        m = fmaxf(m, fmaxf(fmaxf(fabsf(v.x), fabsf(v.y)), fmaxf(fabsf(v.z), fabsf(v.w))));
    }
    m = wmaxf(m);
    if ((threadIdx.x & 63) == 0) atomicMax(&scal[z], __builtin_bit_cast(u32, m));
}

// fq(W) values stored f32: clip(rintf(w*s))/s, all IEEE f32
__global__ void fqw_kernel(const float* __restrict__ wq, const float* __restrict__ wk,
                           const float* __restrict__ wv, float* __restrict__ oq,
                           float* __restrict__ ok, float* __restrict__ ov,
                           const u32* __restrict__ scal) {
    const int z = blockIdx.z;
    const float* w = z == 0 ? wq : z == 1 ? wk : wv;
    float* o = z == 0 ? oq : z == 1 ? ok : ov;
    const float s = 127.0f / fmaxf(ldb(scal, z), 1e-8f);
    int idx = blockIdx.x * 256 + threadIdx.x;
    float4 v = ((const float4*)w)[idx];
    float4 r;
    r.x = clip8f(rintf(fmul(v.x, s))) / s;
    r.y = clip8f(rintf(fmul(v.y, s))) / s;
    r.z = clip8f(rintf(fmul(v.z, s))) / s;
    r.w = clip8f(rintf(fmul(v.w, s))) / s;
    ((float4*)o)[idx] = r;
}

// numpy contig_two GEMM: out[r][c] = sum_d A[r,d]*B[c,d] with 4 strided
// unfused accumulators, combine (a0+a1)+(a2+a3).  16x16 out tile / block.
__global__ __launch_bounds__(256) void np4gemm_xw(
    const float* __restrict__ x, const float* __restrict__ fwq,
    const float* __restrict__ fwk, const float* __restrict__ fwv,
    float* __restrict__ Q, float* __restrict__ K, float* __restrict__ V) {
    const int z = blockIdx.z;
    const float* w = z == 0 ? fwq : z == 1 ? fwk : fwv;
    float* o = z == 0 ? Q : z == 1 ? K : V;
    const int row0 = blockIdx.y * 16, col0 = blockIdx.x * 16;
    const int tid = threadIdx.x, ty = tid >> 4, tx = tid & 15;
    __shared__ float sA[16][68], sB[16][68];
    float a0 = 0.f, a1 = 0.f, a2 = 0.f, a3 = 0.f;
    for (int k0 = 0; k0 < 1024; k0 += 64) {
        int r = tid >> 4, c = (tid & 15) * 4;
        *(float4*)&sA[r][c] = *(const float4*)&x[(size_t)(row0 + r) * 1024 + k0 + c];
        *(float4*)&sB[r][c] = *(const float4*)&w[(size_t)(col0 + r) * 1024 + k0 + c];
        __syncthreads();
        const float* pa = &sA[ty][0];
        const float* pb = &sB[tx][0];
        #pragma unroll
        for (int t = 0; t < 16; ++t) {
            int c4 = t * 4;
            a0 = fadd(a0, fmul(pa[c4 + 0], pb[c4 + 0]));
            a1 = fadd(a1, fmul(pa[c4 + 1], pb[c4 + 1]));
            a2 = fadd(a2, fmul(pa[c4 + 2], pb[c4 + 2]));
            a3 = fadd(a3, fmul(pa[c4 + 3], pb[c4 + 3]));
        }
        __syncthreads();
    }
    o[(size_t)(row0 + ty) * 1024 + col0 + tx] = fadd(fadd(a0, a1), fadd(a2, a3));
}

// atten[b,i,j] = contig_two(Q[b,i,:], K[b,j,:]) + exact f32 amax
__global__ __launch_bounds__(256) void np4gemm_att(
    const float* __restrict__ Q, const float* __restrict__ K,
    float* __restrict__ att, u32* __restrict__ scal) {
    const int b = blockIdx.z;
    const size_t pb = (size_t)b << 20;               // b*1024*1024
    const int row0 = blockIdx.y * 16, col0 = blockIdx.x * 16;
    const int tid = threadIdx.x, ty = tid >> 4, tx = tid & 15;
    __shared__ float sA[16][68], sB[16][68];
    float a0 = 0.f, a1 = 0.f, a2 = 0.f, a3 = 0.f;
    for (int k0 = 0; k0 < 1024; k0 += 64) {
        int r = tid >> 4, c = (tid & 15) * 4;
        *(float4*)&sA[r][c] = *(const float4*)&Q[pb + (size_t)(row0 + r) * 1024 + k0 + c];
        *(float4*)&sB[r][c] = *(const float4*)&K[pb + (size_t)(col0 + r) * 1024 + k0 + c];
        __syncthreads();
        const float* pa = &sA[ty][0];
        const float* pb2 = &sB[tx][0];
        #pragma unroll
        for (int t = 0; t < 16; ++t) {
            int c4 = t * 4;
            a0 = fadd(a0, fmul(pa[c4 + 0], pb2[c4 + 0]));
            a1 = fadd(a1, fmul(pa[c4 + 1], pb2[c4 + 1]));
            a2 = fadd(a2, fmul(pa[c4 + 2], pb2[c4 + 2]));
            a3 = fadd(a3, fmul(pa[c4 + 3], pb2[c4 + 3]));
        }
        __syncthreads();
    }
    float res = fadd(fadd(a0, a1), fadd(a2, a3));
    att[pb + (size_t)(row0 + ty) * 1024 + col0 + tx] = res;
    float lm = wmaxf(fabsf(res));
    if ((tid & 63) == 0) atomicMax(&scal[3], __builtin_bit_cast(u32, lm));
}

// l = fq2( fq1(att)*nq ), all f32, in place.  amax2 = (127/s1)*nq exactly as
// numpy computes the max element of the fq1*nq array.
__global__ void fq_logit_kernel(float* __restrict__ att, const u32* __restrict__ scal) {
    const float s1 = 127.0f / fmaxf(ldb(scal, 3), 1e-8f);
    const float amax2 = fmul(127.0f / s1, 0.03125f);
    const float s2 = 127.0f / fmaxf(amax2, 1e-8f);
    int idx = blockIdx.x * 256 + threadIdx.x;          // 8192 blocks -> 2M f4
    float4 v = ((const float4*)att)[idx];
    float4 r;
    {
        float q = clip8f(rintf(fmul(v.x, s1))); float t = fmul(q / s1, 0.03125f);
        r.x = clip8f(rintf(fmul(t, s2))) / s2;
    }
    {
        float q = clip8f(rintf(fmul(v.y, s1))); float t = fmul(q / s1, 0.03125f);
        r.y = clip8f(rintf(fmul(t, s2))) / s2;
    }
    {
        float q = clip8f(rintf(fmul(v.z, s1))); float t = fmul(q / s1, 0.03125f);
        r.z = clip8f(rintf(fmul(t, s2))) / s2;
    }
    {
        float q = clip8f(rintf(fmul(v.w, s1))); float t = fmul(q / s1, 0.03125f);
        r.w = clip8f(rintf(fmul(t, s2))) / s2;
    }
    ((float4*)att)[idx] = r;
}

// pass A: S[row] = numpy pairwise sum of e; pmax = max(1.0f/S)
__global__ __launch_bounds__(256) void sm_passA(const float* __restrict__ att,
                                                float* __restrict__ Sarr,
                                                u32* __restrict__ scal) {
    const int row = blockIdx.x, tid = threadIdx.x;
    float4 l4 = *(const float4*)&att[(size_t)row * 1024 + tid * 4];
    float m = fmaxf(fmaxf(l4.x, l4.y), fmaxf(l4.z, l4.w));
    m = wmaxf(m);
    __shared__ float redm[4];
    if ((tid & 63) == 0) redm[tid >> 6] = m;
    __syncthreads();
    m = fmaxf(fmaxf(redm[0], redm[1]), fmaxf(redm[2], redm[3]));
    __shared__ float se[1024];
    se[tid * 4 + 0] = expf_np(l4.x - m);
    se[tid * 4 + 1] = expf_np(l4.y - m);
    se[tid * 4 + 2] = expf_np(l4.z - m);
    se[tid * 4 + 3] = expf_np(l4.w - m);
    __syncthreads();
    if (tid == 0) {
        float S = np_pair1024(se);
        Sarr[row] = S;
        float p1 = 1.0f / S;                            // row max prob
        atomicMax(&scal[4], __builtin_bit_cast(u32, p1));
    }
}

// pass B: p = e/S (IEEE f32 div); p_q = clip(rintf(p*s3))/s3, in place
__global__ __launch_bounds__(256) void sm_passB(float* __restrict__ att,
                                                const float* __restrict__ Sarr,
                                                const u32* __restrict__ scal) {
    const int row = blockIdx.x, tid = threadIdx.x;
    float4 l4 = *(const float4*)&att[(size_t)row * 1024 + tid * 4];
    float m = fmaxf(fmaxf(l4.x, l4.y), fmaxf(l4.z, l4.w));
    m = wmaxf(m);
    __shared__ float redm[4];
    if ((tid & 63) == 0) redm[tid >> 6] = m;
    __syncthreads();
    m = fmaxf(fmaxf(redm[0], redm[1]), fmaxf(redm[2], redm[3]));
    const float S = Sarr[row];
    const float s3 = 127.0f / fmaxf(ldb(scal, 4), 1e-8f);
    float4 r;
    { float p = expf_np(l4.x - m) / S; r.x = clip8f(rintf(fmul(p, s3))) / s3; }
    { float p = expf_np(l4.y - m) / S; r.y = clip8f(rintf(fmul(p, s3))) / s3; }
    { float p = expf_np(l4.z - m) / S; r.z = clip8f(rintf(fmul(p, s3))) / s3; }
    { float p = expf_np(l4.w - m) / S; r.w = clip8f(rintf(fmul(p, s3))) / s3; }
    *(float4*)&att[(size_t)row * 1024 + tid * 4] = r;
}

// out[b,i,v] = sequential-j unfused sum of p_q[b,i,j]*V[b,j,v]  (numpy generic
// einsum loop order), + exact f32 amax_out
__global__ __launch_bounds__(256) void pv_seq(const float* __restrict__ pq,
                                              const float* __restrict__ V,
                                              float* __restrict__ out,
                                              u32* __restrict__ scal) {
    const int b = blockIdx.z;
    const size_t pb = (size_t)b << 20;
    const int i0 = blockIdx.y * 16, v0 = blockIdx.x * 16;
    const int tid = threadIdx.x, ty = tid >> 4, tx = tid & 15;
    __shared__ float sP[16][132], sV[128][17];
    float acc = 0.f;
    for (int j0 = 0; j0 < 1024; j0 += 128) {
        {
            int r = tid >> 4, c8 = (tid & 15) * 8;
            const float* g = &pq[pb + (size_t)(i0 + r) * 1024 + j0 + c8];
            *(float4*)&sP[r][c8] = *(const float4*)g;
            *(float4*)&sP[r][c8 + 4] = *(const float4*)(g + 4);
        }
        {
            int jj = tid >> 1, c8 = (tid & 1) * 8;
            const float* g = &V[pb + (size_t)(j0 + jj) * 1024 + v0 + c8];
            *(float4*)&sV[jj][c8] = *(const float4*)g;
            *(float4*)&sV[jj][c8 + 4] = *(const float4*)(g + 4);
        }
        __syncthreads();
        #pragma unroll 16
        for (int jj = 0; jj < 128; ++jj)               // strictly sequential j
            acc = fadd(acc, fmul(sP[ty][jj], sV[jj][tx]));
        __syncthreads();
    }
    out[pb + (size_t)(i0 + ty) * 1024 + v0 + tx] = acc;
    float lm = wmaxf(fabsf(acc));
    if ((tid & 63) == 0) atomicMax(&scal[5], __builtin_bit_cast(u32, lm));
}

__global__ void final_fq_kernel(float* __restrict__ out, const u32* __restrict__ scal) {
    const float s4 = 127.0f / fmaxf(ldb(scal, 5), 1e-8f);
    int idx = blockIdx.x * 256 + threadIdx.x;          // 8192 blocks -> 2M f4
    float4 v = ((float4*)out)[idx];
    v.x = clip8f(rintf(fmul(v.x, s4))) / s4;
    v.y = clip8f(rintf(fmul(v.y, s4))) / s4;
    v.z = clip8f(rintf(fmul(v.z, s4))) / s4;
    v.w = clip8f(rintf(fmul(v.w, s4))) / s4;
    ((float4*)out)[idx] = v;
}

extern "C" void kernel_launch(void* const* d_in, const int* in_sizes, int n_in,
                              void* d_out, int out_size, void* d_ws, size_t ws_size,
                              hipStream_t stream) {
    const float* x  = (const float*)d_in[0];
    const float* Wq = (const float*)d_in[1];
    const float* Wk = (const float*)d_in[2];
    const float* Wv = (const float*)d_in[3];
    // d_in[4] = bit_width, fixed 8 for this problem.
    float* out = (float*)d_out;

    char* ws = (char*)d_ws;
    u32* scal = (u32*)ws;                              // 64 B
    float* Sarr = (float*)(ws + 4096);                 // 32 KB row sums
    const size_t MB = 1024 * 1024;
    size_t off = 65536;
    float* FWQ = (float*)(ws + off); off += 4 * MB;    // fq(Wq) f32
    float* FWK = (float*)(ws + off); off += 4 * MB;
    float* FWV = (float*)(ws + off); off += 4 * MB;
    float* Q   = (float*)(ws + off); off += 32 * MB;   // [8192][1024] f32
    float* K   = (float*)(ws + off); off += 32 * MB;
    float* V   = (float*)(ws + off); off += 32 * MB;
    float* ATT = (float*)(ws + off); off += 32 * MB;   // logits -> l -> p_q
    // total ~140.06 MB (< 166 MB proven available in R2)

    hipLaunchKernelGGL(init_kernel, dim3(1), dim3(64), 0, stream, scal);
    hipLaunchKernelGGL(amax_w_kernel, dim3(128, 1, 3), dim3(256), 0, stream,
                       Wq, Wk, Wv, scal);
    hipLaunchKernelGGL(fqw_kernel, dim3(1024, 1, 3), dim3(256), 0, stream,
                       Wq, Wk, Wv, FWQ, FWK, FWV, scal);
    hipLaunchKernelGGL(np4gemm_xw, dim3(64, 512, 3), dim3(256), 0, stream,
                       x, FWQ, FWK, FWV, Q, K, V);
    hipLaunchKernelGGL(np4gemm_att, dim3(64, 64, 8), dim3(256), 0, stream,
                       Q, K, ATT, scal);
    hipLaunchKernelGGL(fq_logit_kernel, dim3(8192), dim3(256), 0, stream, ATT, scal);
    hipLaunchKernelGGL(sm_passA, dim3(8192), dim3(256), 0, stream, ATT, Sarr, scal);
    hipLaunchKernelGGL(sm_passB, dim3(8192), dim3(256), 0, stream, ATT, Sarr, scal);
    hipLaunchKernelGGL(pv_seq, dim3(64, 64, 8), dim3(256), 0, stream,
                       ATT, V, out, scal);
    hipLaunchKernelGGL(final_fq_kernel, dim3(8192), dim3(256), 0, stream, out, scal);
}